// Round 1
// baseline (81.408 us; speedup 1.0000x reference)
//
#include <hip/hip_runtime.h>

#define HH 768
#define WW 768
#define BC 4
#define NPIX (BC * HH * WW)

typedef float f4 __attribute__((ext_vector_type(4)));
typedef float f2 __attribute__((ext_vector_type(2)));

// 1 output row x 4 cols per thread, incremental ring-sum accumulation.
// Ring sums (by tap r^2): c0,s1,s2,s4,s5,s8 -- 6 accumulators x 4 cols = 24 VGPR
// vs the previous 72-VGPR h[6][4][3] layout. Grid doubles to 2304 blocks
// (9 waves/SIMD supplied); __launch_bounds__(256,8) targets VGPR<=64 so the
// allocator permits 8 waves/SIMD. Halo cols via wave shuffles as before.
__global__ __launch_bounds__(256, 8) void conv_thresh_kernel(
    const float* __restrict__ bev_map,
    const float* __restrict__ bev_scale,
    float* __restrict__ out)  // out[0:N]=conv, out[N:2N]=mask
{
    const int tx = threadIdx.x;                      // 0..63 == lane id
    const int ty = threadIdx.y;                      // 0..3
    const int x0 = (blockIdx.x * 64 + tx) * 4;       // output col base, multiple of 4
    const int oy = blockIdx.y * 4 + ty;              // output row (1 per thread)
    const int b  = blockIdx.z;

    const size_t plane = (size_t)b * (HH * WW);
    const float* __restrict__ m = bev_map + plane;
    const size_t idx = plane + (size_t)oy * WW + x0;

    // Issue the scale load first; its latency hides under the row loop.
    const f4 scv = *(const f4*)(bev_scale + idx);

    // Ring-sum accumulators, indexed by tap distance^2 in the 5x5 window.
    float c0[4], s1[4], s2[4], s4[4], s5[4], s8[4];
#pragma unroll
    for (int j = 0; j < 4; ++j) {
        c0[j] = 0.f; s1[j] = 0.f; s2[j] = 0.f;
        s4[j] = 0.f; s5[j] = 0.f; s8[j] = 0.f;
    }

#pragma unroll
    for (int r = 0; r < 5; ++r) {                    // dy = r - 2
        const int yy = oy - 2 + r;
        const bool yok = (unsigned)yy < (unsigned)HH;   // wave-uniform (ty fixed)
        const float* rowp = m + yy * WW + x0;
        f4 t;
        if (yok) {
            t = *(const f4*)rowp;
            t.x = fmaxf(t.x, 0.f); t.y = fmaxf(t.y, 0.f);
            t.z = fmaxf(t.z, 0.f); t.w = fmaxf(t.w, 0.f);
        } else {
            t.x = 0.f; t.y = 0.f; t.z = 0.f; t.w = 0.f;
        }
        // halo from neighbor lanes (relu already applied)
        float lz = __shfl_up(t.z, 1);    // w[x0-2]
        float lw = __shfl_up(t.w, 1);    // w[x0-1]
        float rx = __shfl_down(t.x, 1);  // w[x0+4]
        float ry = __shfl_down(t.y, 1);  // w[x0+5]
        if (tx == 0) {                   // wave edge: halo lives in another block
            lz = 0.f; lw = 0.f;
            if (yok && x0 != 0) {
                f2 t2 = *(const f2*)(rowp - 2);
                lz = fmaxf(t2.x, 0.f); lw = fmaxf(t2.y, 0.f);
            }
        }
        if (tx == 63) {
            rx = 0.f; ry = 0.f;
            if (yok && x0 != WW - 4) {
                f2 t2 = *(const f2*)(rowp + 4);
                rx = fmaxf(t2.x, 0.f); ry = fmaxf(t2.y, 0.f);
            }
        }
        const float w0 = lz, w1 = lw, w2 = t.x, w3 = t.y,
                    w4 = t.z, w5 = t.w, w6 = rx, w7 = ry;
        // Horizontal partials for this row (consumed immediately).
        const float h0[4] = { w2, w3, w4, w5 };
        const float h1[4] = { w1 + w3, w2 + w4, w3 + w5, w4 + w6 };
        const float h2[4] = { w0 + w4, w1 + w5, w2 + w6, w3 + w7 };
        // dy=+-2 -> r2 = 4,5,8 ; dy=+-1 -> r2 = 1,2,5 ; dy=0 -> r2 = 0,1,4
        if (r == 0 || r == 4) {
#pragma unroll
            for (int j = 0; j < 4; ++j) { s4[j] += h0[j]; s5[j] += h1[j]; s8[j] += h2[j]; }
        } else if (r == 1 || r == 3) {
#pragma unroll
            for (int j = 0; j < 4; ++j) { s1[j] += h0[j]; s2[j] += h1[j]; s5[j] += h2[j]; }
        } else {
#pragma unroll
            for (int j = 0; j < 4; ++j) { c0[j] = h0[j]; s1[j] += h1[j]; s4[j] += h2[j]; }
        }
    }

    f4 conv, mask;
#pragma unroll
    for (int j = 0; j < 4; ++j) {
        const float sc  = scv[j];
        const float den = fmaf(2.0f * sc, sc, 1e-6f);       // 2*sc^2 + eps
        const float t1  = -__builtin_amdgcn_rcpf(den);      // v_rcp_f32: 1ulp, vs ~10-inst IEEE divide
        const float e1  = __expf(t1);                        // w(r2) = e1^r2
        const float e2  = e1 * e1;
        const float e4  = e2 * e2;
        const float e5  = e4 * e1;
        const float e8  = e4 * e4;
        float cv = c0[j];
        cv = fmaf(e1, s1[j], cv);
        cv = fmaf(e2, s2[j], cv);
        cv = fmaf(e4, s4[j], cv);
        cv = fmaf(e5, s5[j], cv);
        cv = fmaf(e8, s8[j], cv);
        conv[j] = cv;
        mask[j] = (cv >= 0.5f) ? 1.0f : 0.0f;
    }
    *(f4*)(out + idx) = conv;
    *(f4*)(out + idx + (size_t)NPIX) = mask;
}

extern "C" void kernel_launch(void* const* d_in, const int* in_sizes, int n_in,
                              void* d_out, int out_size, void* d_ws, size_t ws_size,
                              hipStream_t stream) {
    const float* bev_map   = (const float*)d_in[0];
    const float* bev_scale = (const float*)d_in[1];
    float* out = (float*)d_out;

    dim3 block(64, 4, 1);
    dim3 grid(WW / 256, HH / 4, BC);   // (3, 192, 4) = 2304 blocks, 4 waves each
    conv_thresh_kernel<<<grid, block, 0, stream>>>(bev_map, bev_scale, out);
}

// Round 2
// 74.405 us; speedup vs baseline: 1.0941x; 1.0941x over previous
//
#include <hip/hip_runtime.h>

#define HH 768
#define WW 768
#define BC 4
#define NPIX (BC * HH * WW)

typedef float f4 __attribute__((ext_vector_type(4)));
typedef float f2 __attribute__((ext_vector_type(2)));

// 2 output rows x 4 cols per thread (proven round-0 structure), but the load
// path is fully branchless and shuffle-free: per input row, three naturally-
// aligned loads (b128 @ x0, b64 @ x0-2, b64 @ x0+4) cover w0..w7 directly.
// - no __shfl (DS ops 24 -> 0)
// - no exec-mask branch regions (was 12 divergent regions/thread) -> compiler
//   can hoist ALL 20 VMEM loads into one in-flight batch (phase 1), then
//   compute (phase 2). Targets the exposed-VMEM-latency bottleneck at the
//   grid-limited ~1.1 waves/SIMD occupancy.
// - boundary cols: clamped pointer + cndmask zeroing; boundary rows: clamped
//   row pointer + wave-uniform 0/1 multiplier. All branchless.
__global__ __launch_bounds__(256) void conv_thresh_kernel(
    const float* __restrict__ bev_map,
    const float* __restrict__ bev_scale,
    float* __restrict__ out)  // out[0:N]=conv, out[N:2N]=mask
{
    const int tx = threadIdx.x;                      // 0..63
    const int ty = threadIdx.y;                      // 0..3
    const int x0 = (blockIdx.x * 64 + tx) * 4;       // output col base, mult of 4
    const int y0 = blockIdx.y * 8 + ty * 2;          // output row base, 2 rows/thread
    const int b  = blockIdx.z;

    const size_t plane = (size_t)b * (HH * WW);
    const float* __restrict__ m = bev_map + plane;

    const bool okL = (x0 != 0);
    const bool okR = (x0 != WW - 4);

    // Scale loads issued first; latency hides under the row-load batch.
    const size_t idx0 = plane + (size_t)y0 * WW + x0;
    const f4 sc0v = *(const f4*)(bev_scale + idx0);
    const f4 sc1v = *(const f4*)(bev_scale + idx0 + WW);

    // ---- phase 1: issue all 18 row loads, branchless ----
    f4 A[6];            // w2..w5  (16B aligned)
    f2 L[6];            // w0,w1   (8B aligned @ x0-2)
    f2 R[6];            // w6,w7   (16B aligned @ x0+4)
    float ym[6];        // 0/1 row-validity multiplier (wave-uniform)
#pragma unroll
    for (int r = 0; r < 6; ++r) {
        const int yy  = y0 - 2 + r;
        const int yyc = yy < 0 ? 0 : (yy > HH - 1 ? HH - 1 : yy);
        ym[r] = ((unsigned)yy < (unsigned)HH) ? 1.0f : 0.0f;
        const float* rowp = m + yyc * WW + x0;
        A[r] = *(const f4*)rowp;
        L[r] = *(const f2*)(okL ? rowp - 2 : rowp);   // clamped ptr, values fixed below
        R[r] = *(const f2*)(okR ? rowp + 4 : rowp);
    }

    // ---- phase 2: horizontal partial sums per row ----
    //   h0 = w[x], h1 = w[x-1]+w[x+1], h2 = w[x-2]+w[x+2]   (w = relu(map)*ym)
    float h0[6][4], h1[6][4], h2[6][4];
#pragma unroll
    for (int r = 0; r < 6; ++r) {
        const float mr = ym[r];
        float w0 = okL ? L[r].x : 0.f;
        float w1 = okL ? L[r].y : 0.f;
        float w2 = A[r].x;
        float w3 = A[r].y;
        float w4 = A[r].z;
        float w5 = A[r].w;
        float w6 = okR ? R[r].x : 0.f;
        float w7 = okR ? R[r].y : 0.f;
        w0 = fmaxf(w0, 0.f) * mr;
        w1 = fmaxf(w1, 0.f) * mr;
        w2 = fmaxf(w2, 0.f) * mr;
        w3 = fmaxf(w3, 0.f) * mr;
        w4 = fmaxf(w4, 0.f) * mr;
        w5 = fmaxf(w5, 0.f) * mr;
        w6 = fmaxf(w6, 0.f) * mr;
        w7 = fmaxf(w7, 0.f) * mr;
        h0[r][0] = w2; h1[r][0] = w1 + w3; h2[r][0] = w0 + w4;
        h0[r][1] = w3; h1[r][1] = w2 + w4; h2[r][1] = w1 + w5;
        h0[r][2] = w4; h1[r][2] = w3 + w5; h2[r][2] = w2 + w6;
        h0[r][3] = w5; h1[r][3] = w4 + w6; h2[r][3] = w3 + w7;
    }

    // ---- epilogue: ring sums + Gaussian weights ----
#pragma unroll
    for (int k = 0; k < 2; ++k) {
        const int oy = y0 + k;
        const size_t idx = plane + (size_t)oy * WW + x0;
        const f4 scv = (k == 0) ? sc0v : sc1v;
        f4 conv, mask;
#pragma unroll
        for (int j = 0; j < 4; ++j) {
            // Ring sums by r^2 from horizontal partials (window rows k..k+4)
            const float c0 = h0[k + 2][j];
            const float s1 = h1[k + 2][j] + h0[k + 1][j] + h0[k + 3][j];
            const float s2 = h1[k + 1][j] + h1[k + 3][j];
            const float s4 = h2[k + 2][j] + h0[k][j]     + h0[k + 4][j];
            const float s5 = h2[k + 1][j] + h2[k + 3][j] + h1[k][j] + h1[k + 4][j];
            const float s8 = h2[k][j]     + h2[k + 4][j];

            const float sc  = scv[j];
            const float den = fmaf(2.0f * sc, sc, 1e-6f);   // 2*sc^2 + eps
            const float t1  = -__builtin_amdgcn_rcpf(den);  // v_rcp_f32 (1 ulp)
            const float e1  = __expf(t1);                    // w(r2) = e1^r2
            const float e2  = e1 * e1;
            const float e4  = e2 * e2;
            const float e5  = e4 * e1;
            const float e8  = e4 * e4;

            float cv = c0;
            cv = fmaf(e1, s1, cv);
            cv = fmaf(e2, s2, cv);
            cv = fmaf(e4, s4, cv);
            cv = fmaf(e5, s5, cv);
            cv = fmaf(e8, s8, cv);
            conv[j] = cv;
            mask[j] = (cv >= 0.5f) ? 1.0f : 0.0f;
        }
        *(f4*)(out + idx) = conv;
        *(f4*)(out + idx + (size_t)NPIX) = mask;
    }
}

extern "C" void kernel_launch(void* const* d_in, const int* in_sizes, int n_in,
                              void* d_out, int out_size, void* d_ws, size_t ws_size,
                              hipStream_t stream) {
    const float* bev_map   = (const float*)d_in[0];
    const float* bev_scale = (const float*)d_in[1];
    float* out = (float*)d_out;

    dim3 block(64, 4, 1);
    dim3 grid(WW / 256, HH / 8, BC);   // (3, 96, 4) = 1152 blocks, 4 waves each
    conv_thresh_kernel<<<grid, block, 0, stream>>>(bev_map, bev_scale, out);
}